// Round 1
// baseline (68.759 us; speedup 1.0000x reference)
//
#include <hip/hip_runtime.h>
#include <math.h>

#define NB 16384

// Batch-independent constants staged in LDS (uniform broadcast reads).
struct SConsts {
  float MrT[8][9];  // transpose of Mlist[i][:3,:3], row-major
  float mp[8][3];   // Mlist[i][:3,3]
  float A[7][6];    // screw axes
  float Gd[7][6];   // [Ixx,Iyy,Izz,m,m,m]
  float X7p[3];     // p of adjoint(trans_inv(Mlist[7])); its R is MrT[7]
  float g[3];
  float ftip[6];
};

__device__ __forceinline__ float dot6(const float* a, const float* b) {
  return a[0]*b[0]+a[1]*b[1]+a[2]*b[2]+a[3]*b[3]+a[4]*b[4]+a[5]*b[5];
}

// exp6: matrix exponential of twist (w,v); outputs rotation R (row-major) and p.
__device__ __forceinline__ void exp6_dev(float wx, float wy, float wz,
                                         float vx, float vy, float vz,
                                         float R[9], float p[3]) {
  float th2 = wx*wx + wy*wy + wz*wz;
  float th  = sqrtf(th2);
  bool sm = th < 1e-10f;
  float ths = sm ? 1.0f : th;
  float inv = 1.0f / ths;
  float ux = wx*inv, uy = wy*inv, uz = wz*inv;
  float s, c;
  sincosf(th, &s, &c);
  float omc = 1.0f - c;
  float r00 = c + omc*ux*ux;
  float r01 = omc*ux*uy - s*uz;
  float r02 = omc*ux*uz + s*uy;
  float r10 = omc*uy*ux + s*uz;
  float r11 = c + omc*uy*uy;
  float r12 = omc*uy*uz - s*ux;
  float r20 = omc*uz*ux - s*uy;
  float r21 = omc*uz*uy + s*ux;
  float r22 = c + omc*uz*uz;
  // p = v + (omc/th)(u x v) + ((th-s)/th)(u (u.v) - v)
  float k1 = omc*inv, k2 = (th - s)*inv;
  float cx = uy*vz - uz*vy, cy = uz*vx - ux*vz, cz = ux*vy - uy*vx;
  float udv = ux*vx + uy*vy + uz*vz;
  float px = vx + k1*cx + k2*(ux*udv - vx);
  float py = vy + k1*cy + k2*(uy*udv - vy);
  float pz = vz + k1*cz + k2*(uz*udv - vz);
  R[0]=sm?1.f:r00; R[1]=sm?0.f:r01; R[2]=sm?0.f:r02;
  R[3]=sm?0.f:r10; R[4]=sm?1.f:r11; R[5]=sm?0.f:r12;
  R[6]=sm?0.f:r20; R[7]=sm?0.f:r21; R[8]=sm?1.f:r22;
  p[0]=sm?vx:px; p[1]=sm?vy:py; p[2]=sm?vz:pz;
}

// Adjoint apply: out = Ad(R,p) * in, in = (w,v). top = Rw; bot = p x (Rw) + Rv.
__device__ __forceinline__ void Xapply(const float* R, const float* p,
                                       const float in[6], float out[6]) {
  float a = R[0]*in[0]+R[1]*in[1]+R[2]*in[2];
  float b = R[3]*in[0]+R[4]*in[1]+R[5]*in[2];
  float c = R[6]*in[0]+R[7]*in[1]+R[8]*in[2];
  float d = R[0]*in[3]+R[1]*in[4]+R[2]*in[5];
  float e = R[3]*in[3]+R[4]*in[4]+R[5]*in[5];
  float f = R[6]*in[3]+R[7]*in[4]+R[8]*in[5];
  out[0]=a; out[1]=b; out[2]=c;
  out[3] = p[1]*c - p[2]*b + d;
  out[4] = p[2]*a - p[0]*c + e;
  out[5] = p[0]*b - p[1]*a + f;
}

// Adjoint-transpose apply: in = (m,f). top = R^T (m - p x f); bot = R^T f.
__device__ __forceinline__ void XTapply(const float* R, const float* p,
                                        const float in[6], float out[6]) {
  float fx=in[3], fy=in[4], fz=in[5];
  float tx = in[0] - (p[1]*fz - p[2]*fy);
  float ty = in[1] - (p[2]*fx - p[0]*fz);
  float tz = in[2] - (p[0]*fy - p[1]*fx);
  out[0] = R[0]*tx + R[3]*ty + R[6]*tz;
  out[1] = R[1]*tx + R[4]*ty + R[7]*tz;
  out[2] = R[2]*tx + R[5]*ty + R[8]*tz;
  out[3] = R[0]*fx + R[3]*fy + R[6]*fz;
  out[4] = R[1]*fx + R[4]*fy + R[7]*fz;
  out[5] = R[2]*fx + R[5]*fy + R[8]*fz;
}

// One forward-dynamics evaluation: qacc = M(q)^-1 (tau - h(q,dq)).
__device__ __forceinline__ void derivs_fn(const SConsts& C, const float q[7],
                                          const float dq[7], const float tau[7],
                                          float qacc[7]) {
  // Joint adjoints X_i = Ad(exp6(-A_i q_i) @ trans_inv(Mlist[i])), stored as (R,p).
  float XR[7][9], Xp[7][3];
  #pragma unroll
  for (int i = 0; i < 7; ++i) {
    float Re[9], pe[3];
    float qi = q[i];
    exp6_dev(-C.A[i][0]*qi, -C.A[i][1]*qi, -C.A[i][2]*qi,
             -C.A[i][3]*qi, -C.A[i][4]*qi, -C.A[i][5]*qi, Re, pe);
    #pragma unroll
    for (int r = 0; r < 3; ++r) {
      #pragma unroll
      for (int c = 0; c < 3; ++c)
        XR[i][r*3+c] = Re[r*3+0]*C.MrT[i][0+c] + Re[r*3+1]*C.MrT[i][3+c] + Re[r*3+2]*C.MrT[i][6+c];
      Xp[i][r] = pe[r] - (XR[i][r*3+0]*C.mp[i][0] + XR[i][r*3+1]*C.mp[i][1] + XR[i][r*3+2]*C.mp[i][2]);
    }
  }

  // ---- bias torque h: RNEA with ddq = 0, real gravity/ftip ----
  float V[6]  = {0,0,0,0,0,0};
  float Vd[6] = {0,0,0,-C.g[0],-C.g[1],-C.g[2]};
  float Fb[7][6];  // per-link body force: G Vd - ad(V)^T (G V)
  #pragma unroll
  for (int i = 0; i < 7; ++i) {
    float t[6];
    Xapply(XR[i], Xp[i], V, t);
    float dqi = dq[i];
    #pragma unroll
    for (int k = 0; k < 6; ++k) V[k] = t[k] + C.A[i][k]*dqi;
    Xapply(XR[i], Xp[i], Vd, t);
    float wx=V[0],wy=V[1],wz=V[2],vx=V[3],vy=V[4],vz=V[5];
    float ax=C.A[i][0],ay=C.A[i][1],az=C.A[i][2];
    float bx=C.A[i][3],by=C.A[i][4],bz=C.A[i][5];
    Vd[0] = t[0] + (wy*az - wz*ay)*dqi;
    Vd[1] = t[1] + (wz*ax - wx*az)*dqi;
    Vd[2] = t[2] + (wx*ay - wy*ax)*dqi;
    Vd[3] = t[3] + (vy*az - vz*ay + wy*bz - wz*by)*dqi;
    Vd[4] = t[4] + (vz*ax - vx*az + wz*bx - wx*bz)*dqi;
    Vd[5] = t[5] + (vx*ay - vy*ax + wx*by - wy*bx)*dqi;
    float g0=C.Gd[i][0], g1=C.Gd[i][1], g2=C.Gd[i][2], m=C.Gd[i][3];
    float Gt0=g0*wx, Gt1=g1*wy, Gt2=g2*wz;
    float Gb0=m*vx,  Gb1=m*vy,  Gb2=m*vz;
    // -ad(V)^T u = (w x ut + v x ub, w x ub)
    Fb[i][0] = g0*Vd[0] + (wy*Gt2 - wz*Gt1) + (vy*Gb2 - vz*Gb1);
    Fb[i][1] = g1*Vd[1] + (wz*Gt0 - wx*Gt2) + (vz*Gb0 - vx*Gb2);
    Fb[i][2] = g2*Vd[2] + (wx*Gt1 - wy*Gt0) + (vx*Gb1 - vy*Gb0);
    Fb[i][3] = m*Vd[3] + (wy*Gb2 - wz*Gb1);
    Fb[i][4] = m*Vd[4] + (wz*Gb0 - wx*Gb2);
    Fb[i][5] = m*Vd[5] + (wx*Gb1 - wy*Gb0);
  }
  float h[7];
  float F[6];
  #pragma unroll
  for (int k = 0; k < 6; ++k) F[k] = C.ftip[k];
  #pragma unroll
  for (int i = 6; i >= 0; --i) {
    float t[6];
    if (i == 6) XTapply(C.MrT[7], C.X7p, F, t);   // AdTs[7]^T
    else        XTapply(XR[i+1], Xp[i+1], F, t);
    #pragma unroll
    for (int k = 0; k < 6; ++k) F[k] = t[k] + Fb[i][k];
    h[i] = dot6(F, C.A[i]);
  }

  // ---- mass matrix: unit-vector columns, V == 0, lower triangle + mirror ----
  float Mm[7][7];
  #pragma unroll
  for (int j = 0; j < 7; ++j) {
    float buf[7][6];
    float Vdj[6];
    #pragma unroll
    for (int k = 0; k < 6; ++k) Vdj[k] = C.A[j][k];
    #pragma unroll
    for (int i = j; i < 7; ++i) {
      if (i > j) {
        float t[6];
        Xapply(XR[i], Xp[i], Vdj, t);
        #pragma unroll
        for (int k = 0; k < 6; ++k) Vdj[k] = t[k];
      }
      #pragma unroll
      for (int k = 0; k < 6; ++k) buf[i][k] = C.Gd[i][k]*Vdj[k];
    }
    float Fc[6];
    #pragma unroll
    for (int k = 0; k < 6; ++k) Fc[k] = buf[6][k];  // ftip=0 for M columns
    Mm[6][j] = dot6(Fc, C.A[6]);
    #pragma unroll
    for (int i = 5; i >= j; --i) {
      float t[6];
      XTapply(XR[i+1], Xp[i+1], Fc, t);
      #pragma unroll
      for (int k = 0; k < 6; ++k) Fc[k] = t[k] + buf[i][k];
      Mm[i][j] = dot6(Fc, C.A[i]);
    }
  }
  #pragma unroll
  for (int j = 0; j < 7; ++j)
    #pragma unroll
    for (int i = j+1; i < 7; ++i)
      Mm[j][i] = Mm[i][j];

  // ---- solve M qacc = tau - h (SPD -> no pivoting needed), fully unrolled ----
  float rhs[7];
  #pragma unroll
  for (int i = 0; i < 7; ++i) rhs[i] = tau[i] - h[i];
  #pragma unroll
  for (int k = 0; k < 7; ++k) {
    float inv = 1.0f / Mm[k][k];
    #pragma unroll
    for (int i = k+1; i < 7; ++i) {
      float f = Mm[i][k] * inv;
      #pragma unroll
      for (int c = k+1; c < 7; ++c) Mm[i][c] -= f * Mm[k][c];
      rhs[i] -= f * rhs[k];
    }
  }
  #pragma unroll
  for (int i = 6; i >= 0; --i) {
    float s = rhs[i];
    #pragma unroll
    for (int c = i+1; c < 7; ++c) s -= Mm[i][c] * qacc[c];
    qacc[i] = s / Mm[i][i];
  }
}

extern "C" __global__ void __launch_bounds__(64, 1)
arm_kernel(const float* __restrict__ state, const float* __restrict__ torque,
           const float* __restrict__ Mp, const float* __restrict__ Ain,
           const float* __restrict__ Gp, const float* __restrict__ grav,
           const float* __restrict__ ftip_in, float* __restrict__ out)
{
  __shared__ SConsts C;
  if (threadIdx.x == 0) {
    #pragma unroll
    for (int i = 0; i < 8; ++i) {
      #pragma unroll
      for (int r = 0; r < 3; ++r) {
        #pragma unroll
        for (int c = 0; c < 3; ++c)
          C.MrT[i][c*3 + r] = Mp[i*16 + r*4 + c];
        C.mp[i][r] = Mp[i*16 + r*4 + 3];
      }
    }
    #pragma unroll
    for (int i = 0; i < 7; ++i) {
      #pragma unroll
      for (int k = 0; k < 6; ++k) C.A[i][k] = Ain[i*6 + k];
      C.Gd[i][0] = Gp[i*4+0]; C.Gd[i][1] = Gp[i*4+1]; C.Gd[i][2] = Gp[i*4+2];
      C.Gd[i][3] = C.Gd[i][4] = C.Gd[i][5] = Gp[i*4+3];
    }
    #pragma unroll
    for (int r = 0; r < 3; ++r) {
      C.X7p[r] = -(C.MrT[7][r*3+0]*C.mp[7][0] + C.MrT[7][r*3+1]*C.mp[7][1] + C.MrT[7][r*3+2]*C.mp[7][2]);
      C.g[r] = grav[r];
    }
    #pragma unroll
    for (int k = 0; k < 6; ++k) C.ftip[k] = ftip_in[k];
  }
  __syncthreads();

  int b = blockIdx.x * 64 + threadIdx.x;

  float q0[7], dq0[7], tau[7];
  #pragma unroll
  for (int k = 0; k < 7; ++k) {
    q0[k]  = state[b*14 + k];
    dq0[k] = state[b*14 + 7 + k];
    tau[k] = torque[b*7 + k] * 50.0f;
  }

  // RK4:
  float a[7], accq[7], accdq[7], qc[7], dqc[7];
  derivs_fn(C, q0, dq0, tau, a);                    // a1
  #pragma unroll
  for (int k = 0; k < 7; ++k) {
    accq[k] = dq0[k]; accdq[k] = a[k];
    qc[k]  = q0[k]  + 0.05f*dq0[k];
    dqc[k] = dq0[k] + 0.05f*a[k];
  }
  derivs_fn(C, qc, dqc, tau, a);                    // a2 (inputs q2,dq2)
  #pragma unroll
  for (int k = 0; k < 7; ++k) {
    accq[k] += 2.0f*dqc[k]; accdq[k] += 2.0f*a[k];
    float nq = q0[k] + 0.05f*dqc[k];
    dqc[k] = dq0[k] + 0.05f*a[k];
    qc[k] = nq;
  }
  derivs_fn(C, qc, dqc, tau, a);                    // a3
  #pragma unroll
  for (int k = 0; k < 7; ++k) {
    accq[k] += 2.0f*dqc[k]; accdq[k] += 2.0f*a[k];
    float nq = q0[k] + 0.1f*dqc[k];
    dqc[k] = dq0[k] + 0.1f*a[k];
    qc[k] = nq;
  }
  derivs_fn(C, qc, dqc, tau, a);                    // a4
  #pragma unroll
  for (int k = 0; k < 7; ++k) {
    accq[k] += dqc[k]; accdq[k] += a[k];
  }

  const float c6 = (float)(0.1/6.0);
  const float PI_F = 3.14159265358979323846f;
  const float TWO_PI_F = 6.28318530717958647692f;
  float qw[7];
  #pragma unroll
  for (int k = 0; k < 7; ++k) {
    float q1 = q0[k]  + c6*accq[k];
    float d1 = dq0[k] + c6*accdq[k];
    float y = fmodf(q1 + PI_F, TWO_PI_F);
    y = (y < 0.0f) ? y + TWO_PI_F : y;
    qw[k] = y - PI_F;
    float dqw = fminf(fmaxf(d1, -20.0f), 20.0f);
    out[b*14 + k] = qw[k];
    out[b*14 + 7 + k] = dqw;
  }

  // Forward kinematics with wrapped q.
  float TR[9] = {1,0,0, 0,1,0, 0,0,1};
  float Tp[3] = {0,0,0};
  #pragma unroll
  for (int i = 0; i < 7; ++i) {
    float Rn[9], pn[3];
    #pragma unroll
    for (int r = 0; r < 3; ++r) {
      #pragma unroll
      for (int c = 0; c < 3; ++c)   // Mr[k][c] = MrT[c*3+k]
        Rn[r*3+c] = TR[r*3+0]*C.MrT[i][c*3+0] + TR[r*3+1]*C.MrT[i][c*3+1] + TR[r*3+2]*C.MrT[i][c*3+2];
      pn[r] = TR[r*3+0]*C.mp[i][0] + TR[r*3+1]*C.mp[i][1] + TR[r*3+2]*C.mp[i][2] + Tp[r];
    }
    float Re[9], pe[3];
    float qi = qw[i];
    exp6_dev(C.A[i][0]*qi, C.A[i][1]*qi, C.A[i][2]*qi,
             C.A[i][3]*qi, C.A[i][4]*qi, C.A[i][5]*qi, Re, pe);
    #pragma unroll
    for (int r = 0; r < 3; ++r) {
      #pragma unroll
      for (int c = 0; c < 3; ++c)
        TR[r*3+c] = Rn[r*3+0]*Re[0*3+c] + Rn[r*3+1]*Re[1*3+c] + Rn[r*3+2]*Re[2*3+c];
      Tp[r] = Rn[r*3+0]*pe[0] + Rn[r*3+1]*pe[1] + Rn[r*3+2]*pe[2] + pn[r];
    }
  }
  #pragma unroll
  for (int r = 0; r < 3; ++r) {
    float ee = TR[r*3+0]*C.mp[7][0] + TR[r*3+1]*C.mp[7][1] + TR[r*3+2]*C.mp[7][2] + Tp[r];
    out[NB*14 + b*3 + r] = ee;
  }
}

extern "C" void kernel_launch(void* const* d_in, const int* in_sizes, int n_in,
                              void* d_out, int out_size, void* d_ws, size_t ws_size,
                              hipStream_t stream) {
  const float* state  = (const float*)d_in[0];
  const float* torque = (const float*)d_in[1];
  const float* Mp     = (const float*)d_in[2];
  const float* Ain    = (const float*)d_in[3];
  const float* Gp     = (const float*)d_in[4];
  const float* grav   = (const float*)d_in[5];
  const float* ftip   = (const float*)d_in[6];
  float* out = (float*)d_out;
  hipLaunchKernelGGL(arm_kernel, dim3(NB/64), dim3(64), 0, stream,
                     state, torque, Mp, Ain, Gp, grav, ftip, out);
}

// Round 2
// 36.075 us; speedup vs baseline: 1.9060x; 1.9060x over previous
//
#include <hip/hip_runtime.h>
#include <math.h>

#define NB 16384

// Batch-independent constants staged in LDS (uniform broadcast reads).
struct SConsts {
  float MrT[8][9];  // transpose of Mlist[i][:3,:3], row-major
  float mp[8][3];   // Mlist[i][:3,3]
  float A[7][6];    // screw axes
  float Gd[7][6];   // [Ixx,Iyy,Izz,m,m,m]
  float X7p[3];     // p of adjoint(trans_inv(Mlist[7])); its R is MrT[7]
  float g[3];
  float ftip[6];
};

__device__ __forceinline__ float dot6(const float* a, const float* b) {
  return a[0]*b[0]+a[1]*b[1]+a[2]*b[2]+a[3]*b[3]+a[4]*b[4]+a[5]*b[5];
}

// exp6: matrix exponential of twist (w,v); outputs rotation R (row-major) and p.
__device__ __forceinline__ void exp6_dev(float wx, float wy, float wz,
                                         float vx, float vy, float vz,
                                         float R[9], float p[3]) {
  float th2 = wx*wx + wy*wy + wz*wz;
  float th  = sqrtf(th2);
  bool sm = th < 1e-10f;
  float ths = sm ? 1.0f : th;
  float inv = 1.0f / ths;
  float ux = wx*inv, uy = wy*inv, uz = wz*inv;
  float s, c;
  sincosf(th, &s, &c);
  float omc = 1.0f - c;
  float r00 = c + omc*ux*ux;
  float r01 = omc*ux*uy - s*uz;
  float r02 = omc*ux*uz + s*uy;
  float r10 = omc*uy*ux + s*uz;
  float r11 = c + omc*uy*uy;
  float r12 = omc*uy*uz - s*ux;
  float r20 = omc*uz*ux - s*uy;
  float r21 = omc*uz*uy + s*ux;
  float r22 = c + omc*uz*uz;
  // p = v + (omc/th)(u x v) + ((th-s)/th)(u (u.v) - v)
  float k1 = omc*inv, k2 = (th - s)*inv;
  float cx = uy*vz - uz*vy, cy = uz*vx - ux*vz, cz = ux*vy - uy*vx;
  float udv = ux*vx + uy*vy + uz*vz;
  float px = vx + k1*cx + k2*(ux*udv - vx);
  float py = vy + k1*cy + k2*(uy*udv - vy);
  float pz = vz + k1*cz + k2*(uz*udv - vz);
  R[0]=sm?1.f:r00; R[1]=sm?0.f:r01; R[2]=sm?0.f:r02;
  R[3]=sm?0.f:r10; R[4]=sm?1.f:r11; R[5]=sm?0.f:r12;
  R[6]=sm?0.f:r20; R[7]=sm?0.f:r21; R[8]=sm?1.f:r22;
  p[0]=sm?vx:px; p[1]=sm?vy:py; p[2]=sm?vz:pz;
}

// Adjoint apply: out = Ad(R,p) * in, in = (w,v). top = Rw; bot = p x (Rw) + Rv.
__device__ __forceinline__ void Xapply(const float* R, const float* p,
                                       const float in[6], float out[6]) {
  float a = R[0]*in[0]+R[1]*in[1]+R[2]*in[2];
  float b = R[3]*in[0]+R[4]*in[1]+R[5]*in[2];
  float c = R[6]*in[0]+R[7]*in[1]+R[8]*in[2];
  float d = R[0]*in[3]+R[1]*in[4]+R[2]*in[5];
  float e = R[3]*in[3]+R[4]*in[4]+R[5]*in[5];
  float f = R[6]*in[3]+R[7]*in[4]+R[8]*in[5];
  out[0]=a; out[1]=b; out[2]=c;
  out[3] = p[1]*c - p[2]*b + d;
  out[4] = p[2]*a - p[0]*c + e;
  out[5] = p[0]*b - p[1]*a + f;
}

// Adjoint-transpose apply: in = (m,f). top = R^T (m - p x f); bot = R^T f.
__device__ __forceinline__ void XTapply(const float* R, const float* p,
                                        const float in[6], float out[6]) {
  float fx=in[3], fy=in[4], fz=in[5];
  float tx = in[0] - (p[1]*fz - p[2]*fy);
  float ty = in[1] - (p[2]*fx - p[0]*fz);
  float tz = in[2] - (p[0]*fy - p[1]*fx);
  out[0] = R[0]*tx + R[3]*ty + R[6]*tz;
  out[1] = R[1]*tx + R[4]*ty + R[7]*tz;
  out[2] = R[2]*tx + R[5]*ty + R[8]*tz;
  out[3] = R[0]*fx + R[3]*fy + R[6]*fz;
  out[4] = R[1]*fx + R[4]*fy + R[7]*fz;
  out[5] = R[2]*fx + R[5]*fy + R[8]*fz;
}

// 8 lanes per element. Roles sub=0..6: mass-matrix column j=sub (dq=0, ddq=e_j,
// g=0, ftip=0). Role sub=7: bias torque h (real dq, ddq=0, real g, ftip).
// One generalized RNEA covers all roles with per-lane scalars -> no divergence.
extern "C" __global__ void __launch_bounds__(64, 2)
arm_kernel(const float* __restrict__ state, const float* __restrict__ torque,
           const float* __restrict__ Mp, const float* __restrict__ Ain,
           const float* __restrict__ Gp, const float* __restrict__ grav,
           const float* __restrict__ ftip_in, float* __restrict__ out)
{
  __shared__ SConsts C;
  __shared__ float XL[8][84];   // per element: 7 joints x (R 9 + p 3)
  const int t = threadIdx.x;

  // Cooperative constant staging.
  {
    int i = t >> 3;
    #pragma unroll
    for (int kk = (t & 7); kk < 12; kk += 8) {
      if (kk < 9) {
        int r = kk / 3, c = kk - 3*(kk/3);
        C.MrT[i][c*3 + r] = Mp[i*16 + r*4 + c];
      } else {
        int r = kk - 9;
        C.mp[i][r] = Mp[i*16 + r*4 + 3];
      }
    }
    if (t < 42) {
      int i2 = t / 6, k = t - 6*(t/6);
      C.A[i2][k] = Ain[t];
      C.Gd[i2][k] = (k < 3) ? Gp[i2*4 + k] : Gp[i2*4 + 3];
    }
    if (t < 3) C.g[t] = grav[t];
    if (t < 6) C.ftip[t] = ftip_in[t];
  }
  __syncthreads();
  if (t < 3)
    C.X7p[t] = -(C.MrT[7][t*3+0]*C.mp[7][0] + C.MrT[7][t*3+1]*C.mp[7][1] + C.MrT[7][t*3+2]*C.mp[7][2]);

  const int sub = t & 7;
  const int e   = t >> 3;
  const int b   = blockIdx.x * 8 + e;

  float q0[7], dq0[7], tau[7];
  #pragma unroll
  for (int k = 0; k < 7; ++k) {
    q0[k]  = state[b*14 + k];
    dq0[k] = state[b*14 + 7 + k];
    tau[k] = torque[b*7 + k] * 50.0f;
  }

  float qs[7], dqs[7], accq[7], accdq[7], a[7];
  #pragma unroll
  for (int k = 0; k < 7; ++k) { qs[k]=q0[k]; dqs[k]=dq0[k]; accq[k]=0.0f; accdq[k]=0.0f; }

  const float gm = (sub == 7) ? 1.0f : 0.0f;

  #pragma unroll 1
  for (int stage = 0; stage < 4; ++stage) {
    __syncthreads();   // protect XL against prev-stage readers (and publish X7p on stage 0)
    if (sub < 7) {
      // select qs[sub] with static indices (avoid runtime reg-array index -> scratch)
      float qi = qs[0];
      #pragma unroll
      for (int j = 1; j < 7; ++j) qi = (sub == j) ? qs[j] : qi;
      float Re[9], pe[3];
      exp6_dev(-C.A[sub][0]*qi, -C.A[sub][1]*qi, -C.A[sub][2]*qi,
               -C.A[sub][3]*qi, -C.A[sub][4]*qi, -C.A[sub][5]*qi, Re, pe);
      float Xr[12];
      #pragma unroll
      for (int r = 0; r < 3; ++r) {
        #pragma unroll
        for (int c = 0; c < 3; ++c)
          Xr[r*3+c] = Re[r*3+0]*C.MrT[sub][0+c] + Re[r*3+1]*C.MrT[sub][3+c] + Re[r*3+2]*C.MrT[sub][6+c];
      }
      #pragma unroll
      for (int r = 0; r < 3; ++r)
        Xr[9+r] = pe[r] - (Xr[r*3+0]*C.mp[sub][0] + Xr[r*3+1]*C.mp[sub][1] + Xr[r*3+2]*C.mp[sub][2]);
      float4* dst = (float4*)&XL[e][sub*12];
      dst[0] = make_float4(Xr[0],Xr[1],Xr[2],Xr[3]);
      dst[1] = make_float4(Xr[4],Xr[5],Xr[6],Xr[7]);
      dst[2] = make_float4(Xr[8],Xr[9],Xr[10],Xr[11]);
    }
    __syncthreads();

    // ---- generalized RNEA (per-role dq/ddq/g/ftip) ----
    float V[6] = {0,0,0,0,0,0};
    float Vd[6];
    Vd[0]=0.0f; Vd[1]=0.0f; Vd[2]=0.0f;
    Vd[3] = -gm*C.g[0]; Vd[4] = -gm*C.g[1]; Vd[5] = -gm*C.g[2];
    float Fb[7][6];
    #pragma unroll
    for (int i = 0; i < 7; ++i) {
      const float4* sx = (const float4*)&XL[e][i*12];
      float4 x0 = sx[0], x1 = sx[1], x2 = sx[2];
      float Xr[12] = {x0.x,x0.y,x0.z,x0.w, x1.x,x1.y,x1.z,x1.w, x2.x,x2.y,x2.z,x2.w};
      float dqi  = (sub == 7) ? dqs[i] : 0.0f;
      float ddqi = (sub == i) ? 1.0f : 0.0f;
      float tv[6];
      Xapply(Xr, Xr+9, V, tv);
      #pragma unroll
      for (int k = 0; k < 6; ++k) V[k] = tv[k] + C.A[i][k]*dqi;
      Xapply(Xr, Xr+9, Vd, tv);
      float wx=V[0],wy=V[1],wz=V[2],vx=V[3],vy=V[4],vz=V[5];
      float ax=C.A[i][0],ay=C.A[i][1],az=C.A[i][2];
      float bx=C.A[i][3],by=C.A[i][4],bz=C.A[i][5];
      Vd[0] = tv[0] + ax*ddqi + (wy*az - wz*ay)*dqi;
      Vd[1] = tv[1] + ay*ddqi + (wz*ax - wx*az)*dqi;
      Vd[2] = tv[2] + az*ddqi + (wx*ay - wy*ax)*dqi;
      Vd[3] = tv[3] + bx*ddqi + (vy*az - vz*ay + wy*bz - wz*by)*dqi;
      Vd[4] = tv[4] + by*ddqi + (vz*ax - vx*az + wz*bx - wx*bz)*dqi;
      Vd[5] = tv[5] + bz*ddqi + (vx*ay - vy*ax + wx*by - wy*bx)*dqi;
      float g0=C.Gd[i][0], g1=C.Gd[i][1], g2=C.Gd[i][2], m=C.Gd[i][3];
      float Gt0=g0*wx, Gt1=g1*wy, Gt2=g2*wz;
      float Gb0=m*vx,  Gb1=m*vy,  Gb2=m*vz;
      Fb[i][0] = g0*Vd[0] + (wy*Gt2 - wz*Gt1) + (vy*Gb2 - vz*Gb1);
      Fb[i][1] = g1*Vd[1] + (wz*Gt0 - wx*Gt2) + (vz*Gb0 - vx*Gb2);
      Fb[i][2] = g2*Vd[2] + (wx*Gt1 - wy*Gt0) + (vx*Gb1 - vy*Gb0);
      Fb[i][3] = m*Vd[3] + (wy*Gb2 - wz*Gb1);
      Fb[i][4] = m*Vd[4] + (wz*Gb0 - wx*Gb2);
      Fb[i][5] = m*Vd[5] + (wx*Gb1 - wy*Gb0);
    }
    float col[7];
    float F[6];
    #pragma unroll
    for (int k = 0; k < 6; ++k) F[k] = gm*C.ftip[k];
    #pragma unroll
    for (int i = 6; i >= 0; --i) {
      float tv[6];
      if (i == 6) {
        XTapply(C.MrT[7], C.X7p, F, tv);
      } else {
        const float4* sx = (const float4*)&XL[e][(i+1)*12];
        float4 x0 = sx[0], x1 = sx[1], x2 = sx[2];
        float Xr[12] = {x0.x,x0.y,x0.z,x0.w, x1.x,x1.y,x1.z,x1.w, x2.x,x2.y,x2.z,x2.w};
        XTapply(Xr, Xr+9, F, tv);
      }
      #pragma unroll
      for (int k = 0; k < 6; ++k) F[k] = tv[k] + Fb[i][k];
      col[i] = dot6(F, C.A[i]);
    }

    // ---- gather full M + rhs into every lane (wave-synchronous shuffles) ----
    float Mm[7][7], rhs[7];
    #pragma unroll
    for (int i = 0; i < 7; ++i) {
      #pragma unroll
      for (int j = 0; j < 7; ++j)
        Mm[i][j] = __shfl(col[i], j, 8);
      rhs[i] = tau[i] - __shfl(col[i], 7, 8);
    }

    // ---- solve M a = rhs (SPD, no pivot), redundantly on all 8 lanes ----
    #pragma unroll
    for (int k = 0; k < 7; ++k) {
      float inv = 1.0f / Mm[k][k];
      #pragma unroll
      for (int i2 = k+1; i2 < 7; ++i2) {
        float f = Mm[i2][k] * inv;
        #pragma unroll
        for (int c2 = k+1; c2 < 7; ++c2) Mm[i2][c2] -= f * Mm[k][c2];
        rhs[i2] -= f * rhs[k];
      }
    }
    #pragma unroll
    for (int i2 = 6; i2 >= 0; --i2) {
      float s = rhs[i2];
      #pragma unroll
      for (int c2 = i2+1; c2 < 7; ++c2) s -= Mm[i2][c2] * a[c2];
      a[i2] = s / Mm[i2][i2];
    }

    // ---- RK4 accumulate / advance ----
    float w = (stage == 1 || stage == 2) ? 2.0f : 1.0f;
    #pragma unroll
    for (int k = 0; k < 7; ++k) { accq[k] += w*dqs[k]; accdq[k] += w*a[k]; }
    if (stage < 3) {
      float cc = (stage == 2) ? 0.1f : 0.05f;
      #pragma unroll
      for (int k = 0; k < 7; ++k) {
        float nq = q0[k] + cc*dqs[k];
        dqs[k] = dq0[k] + cc*a[k];
        qs[k] = nq;
      }
    }
  }

  const float c6 = (float)(0.1/6.0);
  const float PI_F = 3.14159265358979323846f;
  const float TWO_PI_F = 6.28318530717958647692f;
  float qw[7];
  #pragma unroll
  for (int k = 0; k < 7; ++k) {
    float q1 = q0[k]  + c6*accq[k];
    float d1 = dq0[k] + c6*accdq[k];
    float y = fmodf(q1 + PI_F, TWO_PI_F);
    y = (y < 0.0f) ? y + TWO_PI_F : y;
    qw[k] = y - PI_F;
    float dqw = fminf(fmaxf(d1, -20.0f), 20.0f);
    if (sub == k) {
      out[b*14 + k] = qw[k];
      out[b*14 + 7 + k] = dqw;
    }
  }

  // Forward kinematics with wrapped q (duplicated on all 8 lanes; 3 lanes write).
  float TR[9] = {1,0,0, 0,1,0, 0,0,1};
  float Tp[3] = {0,0,0};
  #pragma unroll
  for (int i = 0; i < 7; ++i) {
    float Rn[9], pn[3];
    #pragma unroll
    for (int r = 0; r < 3; ++r) {
      #pragma unroll
      for (int c = 0; c < 3; ++c)   // Mr[k][c] = MrT[c*3+k]
        Rn[r*3+c] = TR[r*3+0]*C.MrT[i][c*3+0] + TR[r*3+1]*C.MrT[i][c*3+1] + TR[r*3+2]*C.MrT[i][c*3+2];
      pn[r] = TR[r*3+0]*C.mp[i][0] + TR[r*3+1]*C.mp[i][1] + TR[r*3+2]*C.mp[i][2] + Tp[r];
    }
    float Re[9], pe[3];
    float qi = qw[i];
    exp6_dev(C.A[i][0]*qi, C.A[i][1]*qi, C.A[i][2]*qi,
             C.A[i][3]*qi, C.A[i][4]*qi, C.A[i][5]*qi, Re, pe);
    #pragma unroll
    for (int r = 0; r < 3; ++r) {
      #pragma unroll
      for (int c = 0; c < 3; ++c)
        TR[r*3+c] = Rn[r*3+0]*Re[0*3+c] + Rn[r*3+1]*Re[1*3+c] + Rn[r*3+2]*Re[2*3+c];
      Tp[r] = Rn[r*3+0]*pe[0] + Rn[r*3+1]*pe[1] + Rn[r*3+2]*pe[2] + pn[r];
    }
  }
  float ee[3];
  #pragma unroll
  for (int r = 0; r < 3; ++r)
    ee[r] = TR[r*3+0]*C.mp[7][0] + TR[r*3+1]*C.mp[7][1] + TR[r*3+2]*C.mp[7][2] + Tp[r];
  #pragma unroll
  for (int r = 0; r < 3; ++r)
    if (sub == r) out[NB*14 + b*3 + r] = ee[r];
}

extern "C" void kernel_launch(void* const* d_in, const int* in_sizes, int n_in,
                              void* d_out, int out_size, void* d_ws, size_t ws_size,
                              hipStream_t stream) {
  const float* state  = (const float*)d_in[0];
  const float* torque = (const float*)d_in[1];
  const float* Mp     = (const float*)d_in[2];
  const float* Ain    = (const float*)d_in[3];
  const float* Gp     = (const float*)d_in[4];
  const float* grav   = (const float*)d_in[5];
  const float* ftip   = (const float*)d_in[6];
  float* out = (float*)d_out;
  hipLaunchKernelGGL(arm_kernel, dim3(NB/8), dim3(64), 0, stream,
                     state, torque, Mp, Ain, Gp, grav, ftip, out);
}

// Round 3
// 26.521 us; speedup vs baseline: 2.5926x; 1.3602x over previous
//
#include <hip/hip_runtime.h>
#include <math.h>

#define NB 16384

// Batch-independent constants staged in LDS (uniform broadcast reads).
struct SConsts {
  float MrT[8][9];  // transpose of Mlist[i][:3,:3], row-major
  float mp[8][3];   // Mlist[i][:3,3]
  float A[7][6];    // screw axes
  float Gd[7][6];   // [Ixx,Iyy,Izz,m,m,m]
  float X7p[3];     // p of adjoint(trans_inv(Mlist[7])); its R is MrT[7]
  float g[3];
  float ftip[6];
};

__device__ __forceinline__ float dot6(const float* a, const float* b) {
  return a[0]*b[0]+a[1]*b[1]+a[2]*b[2]+a[3]*b[3]+a[4]*b[4]+a[5]*b[5];
}

// exp6 with native sin/cos/sqrt/rcp (1-2 ulp; threshold 0.4 >> effect).
__device__ __forceinline__ void exp6_dev(float wx, float wy, float wz,
                                         float vx, float vy, float vz,
                                         float R[9], float p[3]) {
  float th2 = wx*wx + wy*wy + wz*wz;
  float th  = __builtin_amdgcn_sqrtf(th2);
  bool sm = th < 1e-10f;
  float ths = sm ? 1.0f : th;
  float inv = __builtin_amdgcn_rcpf(ths);
  float ux = wx*inv, uy = wy*inv, uz = wz*inv;
  float s = __sinf(th);
  float c = __cosf(th);
  float omc = 1.0f - c;
  float r00 = c + omc*ux*ux;
  float r01 = omc*ux*uy - s*uz;
  float r02 = omc*ux*uz + s*uy;
  float r10 = omc*uy*ux + s*uz;
  float r11 = c + omc*uy*uy;
  float r12 = omc*uy*uz - s*ux;
  float r20 = omc*uz*ux - s*uy;
  float r21 = omc*uz*uy + s*ux;
  float r22 = c + omc*uz*uz;
  float k1 = omc*inv, k2 = (th - s)*inv;
  float cx = uy*vz - uz*vy, cy = uz*vx - ux*vz, cz = ux*vy - uy*vx;
  float udv = ux*vx + uy*vy + uz*vz;
  float px = vx + k1*cx + k2*(ux*udv - vx);
  float py = vy + k1*cy + k2*(uy*udv - vy);
  float pz = vz + k1*cz + k2*(uz*udv - vz);
  R[0]=sm?1.f:r00; R[1]=sm?0.f:r01; R[2]=sm?0.f:r02;
  R[3]=sm?0.f:r10; R[4]=sm?1.f:r11; R[5]=sm?0.f:r12;
  R[6]=sm?0.f:r20; R[7]=sm?0.f:r21; R[8]=sm?1.f:r22;
  p[0]=sm?vx:px; p[1]=sm?vy:py; p[2]=sm?vz:pz;
}

// Adjoint apply: out = Ad(R,p) * in, in = (w,v). top = Rw; bot = p x (Rw) + Rv.
__device__ __forceinline__ void Xapply(const float* R, const float* p,
                                       const float in[6], float out[6]) {
  float a = R[0]*in[0]+R[1]*in[1]+R[2]*in[2];
  float b = R[3]*in[0]+R[4]*in[1]+R[5]*in[2];
  float c = R[6]*in[0]+R[7]*in[1]+R[8]*in[2];
  float d = R[0]*in[3]+R[1]*in[4]+R[2]*in[5];
  float e = R[3]*in[3]+R[4]*in[4]+R[5]*in[5];
  float f = R[6]*in[3]+R[7]*in[4]+R[8]*in[5];
  out[0]=a; out[1]=b; out[2]=c;
  out[3] = p[1]*c - p[2]*b + d;
  out[4] = p[2]*a - p[0]*c + e;
  out[5] = p[0]*b - p[1]*a + f;
}

// Adjoint-transpose apply: in = (m,f). top = R^T (m - p x f); bot = R^T f.
__device__ __forceinline__ void XTapply(const float* R, const float* p,
                                        const float in[6], float out[6]) {
  float fx=in[3], fy=in[4], fz=in[5];
  float tx = in[0] - (p[1]*fz - p[2]*fy);
  float ty = in[1] - (p[2]*fx - p[0]*fz);
  float tz = in[2] - (p[0]*fy - p[1]*fx);
  out[0] = R[0]*tx + R[3]*ty + R[6]*tz;
  out[1] = R[1]*tx + R[4]*ty + R[7]*tz;
  out[2] = R[2]*tx + R[5]*ty + R[8]*tz;
  out[3] = R[0]*fx + R[3]*fy + R[6]*fz;
  out[4] = R[1]*fx + R[4]*fy + R[7]*fz;
  out[5] = R[2]*fx + R[5]*fy + R[8]*fz;
}

// 8 lanes per element. Roles sub=0..6: mass-matrix column j=sub (dq=0, ddq=e_j,
// g=0, ftip=0). Role sub=7: bias torque h (real dq, ddq=0, real g, ftip).
extern "C" __global__ void __launch_bounds__(64, 2)
arm_kernel(const float* __restrict__ state, const float* __restrict__ torque,
           const float* __restrict__ Mp, const float* __restrict__ Ain,
           const float* __restrict__ Gp, const float* __restrict__ grav,
           const float* __restrict__ ftip_in, float* __restrict__ out)
{
  __shared__ SConsts C;
  __shared__ float XL[8][100];  // per element: 7 joints x (R 9 + p 3); stride 100 dwords (bank-spread)
  __shared__ float CL[8][68];   // per element: column gather, CL[e][k*8+sub]
  const int t = threadIdx.x;

  // Cooperative constant staging.
  {
    int i = t >> 3;
    #pragma unroll
    for (int kk = (t & 7); kk < 12; kk += 8) {
      if (kk < 9) {
        int r = kk / 3, c = kk - 3*(kk/3);
        C.MrT[i][c*3 + r] = Mp[i*16 + r*4 + c];
      } else {
        int r = kk - 9;
        C.mp[i][r] = Mp[i*16 + r*4 + 3];
      }
    }
    if (t < 42) {
      int i2 = t / 6, k = t - 6*(t/6);
      C.A[i2][k] = Ain[t];
      C.Gd[i2][k] = (k < 3) ? Gp[i2*4 + k] : Gp[i2*4 + 3];
    }
    if (t < 3) C.g[t] = grav[t];
    if (t < 6) C.ftip[t] = ftip_in[t];
  }
  __syncthreads();
  if (t < 3)
    C.X7p[t] = -(C.MrT[7][t*3+0]*C.mp[7][0] + C.MrT[7][t*3+1]*C.mp[7][1] + C.MrT[7][t*3+2]*C.mp[7][2]);

  const int sub = t & 7;
  const int e   = t >> 3;
  const int b   = blockIdx.x * 8 + e;

  float q0[7], dq0[7], tau[7];
  #pragma unroll
  for (int k = 0; k < 7; ++k) {
    q0[k]  = state[b*14 + k];
    dq0[k] = state[b*14 + 7 + k];
    tau[k] = torque[b*7 + k] * 50.0f;
  }

  float qs[7], dqs[7], accq[7], accdq[7], a[7];
  #pragma unroll
  for (int k = 0; k < 7; ++k) { qs[k]=q0[k]; dqs[k]=dq0[k]; accq[k]=0.0f; accdq[k]=0.0f; }

  const float gm = (sub == 7) ? 1.0f : 0.0f;

  #pragma unroll 1
  for (int stage = 0; stage < 4; ++stage) {
    __syncthreads();   // XL safe to overwrite (also publishes X7p on stage 0)
    if (sub < 7) {
      float qi = qs[0];
      #pragma unroll
      for (int j = 1; j < 7; ++j) qi = (sub == j) ? qs[j] : qi;
      float Re[9], pe[3];
      exp6_dev(-C.A[sub][0]*qi, -C.A[sub][1]*qi, -C.A[sub][2]*qi,
               -C.A[sub][3]*qi, -C.A[sub][4]*qi, -C.A[sub][5]*qi, Re, pe);
      float Xr[12];
      #pragma unroll
      for (int r = 0; r < 3; ++r) {
        #pragma unroll
        for (int c = 0; c < 3; ++c)
          Xr[r*3+c] = Re[r*3+0]*C.MrT[sub][0+c] + Re[r*3+1]*C.MrT[sub][3+c] + Re[r*3+2]*C.MrT[sub][6+c];
      }
      #pragma unroll
      for (int r = 0; r < 3; ++r)
        Xr[9+r] = pe[r] - (Xr[r*3+0]*C.mp[sub][0] + Xr[r*3+1]*C.mp[sub][1] + Xr[r*3+2]*C.mp[sub][2]);
      float4* dst = (float4*)&XL[e][sub*12];
      dst[0] = make_float4(Xr[0],Xr[1],Xr[2],Xr[3]);
      dst[1] = make_float4(Xr[4],Xr[5],Xr[6],Xr[7]);
      dst[2] = make_float4(Xr[8],Xr[9],Xr[10],Xr[11]);
    }
    __syncthreads();

    // ---- generalized RNEA (per-role dq/ddq/g/ftip) ----
    float V[6] = {0,0,0,0,0,0};
    float Vd[6];
    Vd[0]=0.0f; Vd[1]=0.0f; Vd[2]=0.0f;
    Vd[3] = -gm*C.g[0]; Vd[4] = -gm*C.g[1]; Vd[5] = -gm*C.g[2];
    float Fb[7][6];
    #pragma unroll
    for (int i = 0; i < 7; ++i) {
      const float4* sx = (const float4*)&XL[e][i*12];
      float4 x0 = sx[0], x1 = sx[1], x2 = sx[2];
      float Xr[12] = {x0.x,x0.y,x0.z,x0.w, x1.x,x1.y,x1.z,x1.w, x2.x,x2.y,x2.z,x2.w};
      float dqi  = (sub == 7) ? dqs[i] : 0.0f;
      float ddqi = (sub == i) ? 1.0f : 0.0f;
      float tv[6];
      Xapply(Xr, Xr+9, V, tv);
      #pragma unroll
      for (int k = 0; k < 6; ++k) V[k] = tv[k] + C.A[i][k]*dqi;
      Xapply(Xr, Xr+9, Vd, tv);
      float wx=V[0],wy=V[1],wz=V[2],vx=V[3],vy=V[4],vz=V[5];
      float ax=C.A[i][0],ay=C.A[i][1],az=C.A[i][2];
      float bx=C.A[i][3],by=C.A[i][4],bz=C.A[i][5];
      Vd[0] = tv[0] + ax*ddqi + (wy*az - wz*ay)*dqi;
      Vd[1] = tv[1] + ay*ddqi + (wz*ax - wx*az)*dqi;
      Vd[2] = tv[2] + az*ddqi + (wx*ay - wy*ax)*dqi;
      Vd[3] = tv[3] + bx*ddqi + (vy*az - vz*ay + wy*bz - wz*by)*dqi;
      Vd[4] = tv[4] + by*ddqi + (vz*ax - vx*az + wz*bx - wx*bz)*dqi;
      Vd[5] = tv[5] + bz*ddqi + (vx*ay - vy*ax + wx*by - wy*bx)*dqi;
      float g0=C.Gd[i][0], g1=C.Gd[i][1], g2=C.Gd[i][2], m=C.Gd[i][3];
      float Gt0=g0*wx, Gt1=g1*wy, Gt2=g2*wz;
      float Gb0=m*vx,  Gb1=m*vy,  Gb2=m*vz;
      Fb[i][0] = g0*Vd[0] + (wy*Gt2 - wz*Gt1) + (vy*Gb2 - vz*Gb1);
      Fb[i][1] = g1*Vd[1] + (wz*Gt0 - wx*Gt2) + (vz*Gb0 - vx*Gb2);
      Fb[i][2] = g2*Vd[2] + (wx*Gt1 - wy*Gt0) + (vx*Gb1 - vy*Gb0);
      Fb[i][3] = m*Vd[3] + (wy*Gb2 - wz*Gb1);
      Fb[i][4] = m*Vd[4] + (wz*Gb0 - wx*Gb2);
      Fb[i][5] = m*Vd[5] + (wx*Gb1 - wy*Gb0);
    }
    float col[7];
    float F[6];
    #pragma unroll
    for (int k = 0; k < 6; ++k) F[k] = gm*C.ftip[k];
    #pragma unroll
    for (int i = 6; i >= 0; --i) {
      float tv[6];
      if (i == 6) {
        XTapply(C.MrT[7], C.X7p, F, tv);
      } else {
        const float4* sx = (const float4*)&XL[e][(i+1)*12];
        float4 x0 = sx[0], x1 = sx[1], x2 = sx[2];
        float Xr[12] = {x0.x,x0.y,x0.z,x0.w, x1.x,x1.y,x1.z,x1.w, x2.x,x2.y,x2.z,x2.w};
        XTapply(Xr, Xr+9, F, tv);
      }
      #pragma unroll
      for (int k = 0; k < 6; ++k) F[k] = tv[k] + Fb[i][k];
      col[i] = dot6(F, C.A[i]);
    }

    // ---- gather full M + rhs via LDS (b128 row reads; stride-68 rows -> 2-way = free) ----
    __syncthreads();
    #pragma unroll
    for (int k = 0; k < 7; ++k) CL[e][k*8 + sub] = col[k];
    __syncthreads();
    float Mm[7][7], rhs[7];
    #pragma unroll
    for (int i = 0; i < 7; ++i) {
      const float4* rp = (const float4*)&CL[e][i*8];
      float4 r0 = rp[0], r1 = rp[1];
      Mm[i][0]=r0.x; Mm[i][1]=r0.y; Mm[i][2]=r0.z; Mm[i][3]=r0.w;
      Mm[i][4]=r1.x; Mm[i][5]=r1.y; Mm[i][6]=r1.z;
      rhs[i] = tau[i] - r1.w;
    }

    // ---- solve M a = rhs (SPD, no pivot); pivot reciprocals via v_rcp ----
    float invd[7];
    #pragma unroll
    for (int k = 0; k < 7; ++k) {
      invd[k] = __builtin_amdgcn_rcpf(Mm[k][k]);
      #pragma unroll
      for (int i2 = k+1; i2 < 7; ++i2) {
        float f = Mm[i2][k] * invd[k];
        #pragma unroll
        for (int c2 = k+1; c2 < 7; ++c2) Mm[i2][c2] -= f * Mm[k][c2];
        rhs[i2] -= f * rhs[k];
      }
    }
    #pragma unroll
    for (int i2 = 6; i2 >= 0; --i2) {
      float s = rhs[i2];
      #pragma unroll
      for (int c2 = i2+1; c2 < 7; ++c2) s -= Mm[i2][c2] * a[c2];
      a[i2] = s * invd[i2];
    }

    // ---- RK4 accumulate / advance ----
    float w = (stage == 1 || stage == 2) ? 2.0f : 1.0f;
    #pragma unroll
    for (int k = 0; k < 7; ++k) { accq[k] += w*dqs[k]; accdq[k] += w*a[k]; }
    if (stage < 3) {
      float cc = (stage == 2) ? 0.1f : 0.05f;
      #pragma unroll
      for (int k = 0; k < 7; ++k) {
        float nq = q0[k] + cc*dqs[k];
        dqs[k] = dq0[k] + cc*a[k];
        qs[k] = nq;
      }
    }
  }

  const float c6 = (float)(0.1/6.0);
  const float PI_F = 3.14159265358979323846f;
  const float TWO_PI_F = 6.28318530717958647692f;
  const float INV_TWO_PI_F = 0.15915494309189535f;
  float qw[7], dqw[7];
  #pragma unroll
  for (int k = 0; k < 7; ++k) {
    float q1 = q0[k]  + c6*accq[k];
    float d1 = dq0[k] + c6*accdq[k];
    float x = q1 + PI_F;
    float n = floorf(x * INV_TWO_PI_F);
    float y = fmaf(n, -TWO_PI_F, x);
    y = (y < 0.0f) ? y + TWO_PI_F : y;
    y = (y >= TWO_PI_F) ? y - TWO_PI_F : y;
    qw[k] = y - PI_F;
    dqw[k] = fminf(fmaxf(d1, -20.0f), 20.0f);
  }
  // Each lane sub<7 writes its own joint's outputs (static select, 2 stores).
  {
    float oq = qw[0], od = dqw[0];
    #pragma unroll
    for (int k = 1; k < 7; ++k) { oq = (sub == k) ? qw[k] : oq; od = (sub == k) ? dqw[k] : od; }
    if (sub < 7) {
      out[b*14 + sub] = oq;
      out[b*14 + 7 + sub] = od;
    }
  }

  // ---- FK: lane sub<7 builds its link transform L_sub = M_sub * exp6(A q);
  //      ee = L0·(L1·(...(L6·mp7))) needs only translations (84 FMA chain). ----
  __syncthreads();   // XL safe to overwrite
  if (sub < 7) {
    float qi = qw[0];
    #pragma unroll
    for (int j = 1; j < 7; ++j) qi = (sub == j) ? qw[j] : qi;
    float Re[9], pe[3];
    exp6_dev(C.A[sub][0]*qi, C.A[sub][1]*qi, C.A[sub][2]*qi,
             C.A[sub][3]*qi, C.A[sub][4]*qi, C.A[sub][5]*qi, Re, pe);
    float L[12];
    #pragma unroll
    for (int r = 0; r < 3; ++r) {
      #pragma unroll
      for (int c = 0; c < 3; ++c)   // Mr[r][k] = MrT[k*3+r]
        L[r*3+c] = C.MrT[sub][0*3+r]*Re[0*3+c] + C.MrT[sub][1*3+r]*Re[1*3+c] + C.MrT[sub][2*3+r]*Re[2*3+c];
      L[9+r] = C.MrT[sub][0*3+r]*pe[0] + C.MrT[sub][1*3+r]*pe[1] + C.MrT[sub][2*3+r]*pe[2] + C.mp[sub][r];
    }
    float4* dst = (float4*)&XL[e][sub*12];
    dst[0] = make_float4(L[0],L[1],L[2],L[3]);
    dst[1] = make_float4(L[4],L[5],L[6],L[7]);
    dst[2] = make_float4(L[8],L[9],L[10],L[11]);
  }
  __syncthreads();
  float v0 = C.mp[7][0], v1 = C.mp[7][1], v2 = C.mp[7][2];
  #pragma unroll
  for (int i = 6; i >= 0; --i) {
    const float4* sx = (const float4*)&XL[e][i*12];
    float4 x0 = sx[0], x1 = sx[1], x2 = sx[2];
    float n0 = x0.x*v0 + x0.y*v1 + x0.z*v2 + x2.y;
    float n1 = x0.w*v0 + x1.x*v1 + x1.y*v2 + x2.z;
    float n2 = x1.z*v0 + x1.w*v1 + x2.x*v2 + x2.w;
    v0 = n0; v1 = n1; v2 = n2;
  }
  {
    float ev = v0;
    ev = (sub == 1) ? v1 : ev;
    ev = (sub == 2) ? v2 : ev;
    if (sub < 3) out[NB*14 + b*3 + sub] = ev;
  }
}

extern "C" void kernel_launch(void* const* d_in, const int* in_sizes, int n_in,
                              void* d_out, int out_size, void* d_ws, size_t ws_size,
                              hipStream_t stream) {
  const float* state  = (const float*)d_in[0];
  const float* torque = (const float*)d_in[1];
  const float* Mp     = (const float*)d_in[2];
  const float* Ain    = (const float*)d_in[3];
  const float* Gp     = (const float*)d_in[4];
  const float* grav   = (const float*)d_in[5];
  const float* ftip   = (const float*)d_in[6];
  float* out = (float*)d_out;
  hipLaunchKernelGGL(arm_kernel, dim3(NB/8), dim3(64), 0, stream,
                     state, torque, Mp, Ain, Gp, grav, ftip, out);
}